// Round 14
// baseline (330.418 us; speedup 1.0000x reference)
//
#include <hip/hip_runtime.h>

#define NUM_USERS 100000
#define NUM_ITEMS 50000
#define EMBED_DIM 64
#define N_NODES   (NUM_USERS + NUM_ITEMS)      // 150000
#define N_EDGES   4800000
#define N_QUERY   16384

#define NODE_FLOATS ((size_t)N_NODES * EMBED_DIM)   // 9,600,000
#define NODE_FLOAT4 (NODE_FLOATS / 4)                // 2,400,000

#define NBUCKET    512
#define BROWS      293                               // 512*293 = 150016 rows
#define BUCKET_CAP 10496                              // mean 9375 + ~11.6 sigma
#define BIN_EDGES  4096
#define BIN_THREADS 512
#define BIN_BLOCKS ((N_EDGES + BIN_EDGES - 1) / BIN_EDGES)  // 1172
#define CSR_THREADS 512
#define EGO_SLICE  4688                               // ceil(2.4M / 512)

// ---------------------------------------------------------------------------
// bf16 pack/unpack helpers (RNE)
// ---------------------------------------------------------------------------
__device__ __forceinline__ float4 bf2f4(uint2 u) {
    float4 f;
    f.x = __uint_as_float(u.x << 16);
    f.y = __uint_as_float(u.x & 0xFFFF0000u);
    f.z = __uint_as_float(u.y << 16);
    f.w = __uint_as_float(u.y & 0xFFFF0000u);
    return f;
}
__device__ __forceinline__ unsigned rne_bf(float f) {
    unsigned b = __float_as_uint(f);
    return (b + 0x7FFFu + ((b >> 16) & 1u)) >> 16;
}
__device__ __forceinline__ uint2 f42bf(float4 f) {
    uint2 u;
    u.x = rne_bf(f.x) | (rne_bf(f.y) << 16);
    u.y = rne_bf(f.z) | (rne_bf(f.w) << 16);
    return u;
}
__device__ __forceinline__ void fma4v(float v, float4 xv, float4& av) {
    av.x = fmaf(v, xv.x, av.x);
    av.y = fmaf(v, xv.y, av.y);
    av.z = fmaf(v, xv.z, av.z);
    av.w = fmaf(v, xv.w, av.w);
}

// ---------------------------------------------------------------------------
// bin: single edge read -> 512 row-range buckets (LDS-staged). Dense
// copy-out; emits u16 row-local ids (recRl) for csr's cheap hist.
// LDS ~51 KB -> 3 blocks/CU.
// ---------------------------------------------------------------------------
__global__ void __launch_bounds__(BIN_THREADS) bin_kernel(
        const int* __restrict__ rows,
        const int* __restrict__ cols,
        const float* __restrict__ vals,
        int* __restrict__ gcur,
        int2* __restrict__ rec,
        unsigned short* __restrict__ recRl) {
    __shared__ int  lcnt[NBUCKET];
    __shared__ int  lbase[NBUCKET];
    __shared__ int  loff[NBUCKET];
    __shared__ int  lcur[NBUCKET];
    __shared__ int  scan[NBUCKET];
    __shared__ int2 sRec[BIN_EDGES];
    __shared__ unsigned short sBkt[BIN_EDGES];

    const int tid = threadIdx.x;
    lcnt[tid] = 0;                    // BIN_THREADS == NBUCKET == 512
    __syncthreads();

    const size_t e0 = (size_t)blockIdx.x * BIN_EDGES;
    const int nrec = (int)(((size_t)N_EDGES - e0) < BIN_EDGES ? (N_EDGES - e0)
                                                              : BIN_EDGES);

    // pass 1: bucket counts
    for (int k = tid; k < nrec; k += BIN_THREADS)
        atomicAdd(&lcnt[rows[e0 + k] / BROWS], 1);
    __syncthreads();

    // claim global ranges (gcur zero-based; add bucket region base)
    lbase[tid] = tid * BUCKET_CAP + atomicAdd(&gcur[tid], lcnt[tid]);
    scan[tid]  = lcnt[tid];
    __syncthreads();
    for (int off = 1; off < NBUCKET; off <<= 1) {
        int tv = (tid >= off) ? scan[tid - off] : 0;
        __syncthreads();
        scan[tid] += tv;
        __syncthreads();
    }
    loff[tid] = scan[tid] - lcnt[tid];
    lcur[tid] = loff[tid];
    __syncthreads();

    // pass 2: stage records bucket-sorted in LDS, record bucket per slot
    for (int k = tid; k < nrec; k += BIN_THREADS) {
        int r  = rows[e0 + k];
        int b  = r / BROWS;
        int rl = r - b * BROWS;
        int slot = atomicAdd(&lcur[b], 1);
        sRec[slot] = make_int2((rl << 18) | cols[e0 + k],
                               __float_as_int(vals[e0 + k]));
        sBkt[slot] = (unsigned short)b;
    }
    __syncthreads();

    // dense coalesced copy-out (+ u16 row-local id stream)
    for (int k = tid; k < nrec; k += BIN_THREADS) {
        int bk = sBkt[k];
        int2 r = sRec[k];
        size_t d = (size_t)lbase[bk] + (k - loff[bk]);
        rec[d]   = r;
        recRl[d] = (unsigned short)((unsigned)r.x >> 18);
    }
}

// ---------------------------------------------------------------------------
// csr: one block per bucket (512 blocks -> 2/CU), 512 threads. Hist reads the
// u16 recRl stream; single-level 512-wide scan (even-aligned starts);
// LDS-cursor scatter into the bucket's 84 KB pair slice (L2-resident).
// Fused ego bf16 conversion.
// ---------------------------------------------------------------------------
__global__ void __launch_bounds__(CSR_THREADS) csr_kernel(
        const int2* __restrict__ rec,
        const unsigned short* __restrict__ recRl,
        const int* __restrict__ gcur,
        int* __restrict__ row_start,
        int* __restrict__ row_cnt,
        int2* __restrict__ pair,
        const float4* __restrict__ ue4,
        const float4* __restrict__ ie4,
        uint2* __restrict__ ego) {
    __shared__ int hist[BROWS + 3];
    __shared__ int excl[CSR_THREADS];
    __shared__ int scan[CSR_THREADS];

    const int b    = blockIdx.x;
    const int base = b * BUCKET_CAP;
    const int n    = gcur[b];
    const int lo   = b * BROWS;
    const int t    = threadIdx.x;

    // fused ego bf16 conversion (independent; overlaps hist latency)
    {
        const size_t user_f4 = (size_t)NUM_USERS * EMBED_DIM / 4;
        size_t s0 = (size_t)b * EGO_SLICE;
        for (int j = t; j < EGO_SLICE; j += CSR_THREADS) {
            size_t idx = s0 + j;
            if (idx < NODE_FLOAT4) {
                float4 v = (idx < user_f4) ? ue4[idx] : ie4[idx - user_f4];
                ego[idx] = f42bf(v);
            }
        }
    }

    if (t < BROWS + 3) hist[t] = 0;
    __syncthreads();

    // pass 1: histogram from the compact u16 stream
    for (int i = t; i < n; i += CSR_THREADS)
        atomicAdd(&hist[recRl[base + i]], 1);
    __syncthreads();

    // single-level exclusive scan of even-rounded counts (512-wide)
    int v = (t < BROWS) ? ((hist[t] + 1) & ~1) : 0;
    scan[t] = v;
    __syncthreads();
    for (int off = 1; off < CSR_THREADS; off <<= 1) {
        int tv = (t >= off) ? scan[t - off] : 0;
        __syncthreads();
        scan[t] += tv;
        __syncthreads();
    }
    excl[t] = scan[t] - v;
    __syncthreads();

    if (t < BROWS) {
        row_start[lo + t] = base + excl[t];
        row_cnt[lo + t]   = hist[t];
    }
    __syncthreads();

    // pass 2: scatter; excl doubles as cursors
    for (int i = t; i < n; i += CSR_THREADS) {
        int2 p = rec[base + i];
        int rl = (unsigned)p.x >> 18;
        int slot = atomicAdd(&excl[rl], 1);
        pair[(size_t)base + slot] = make_int2(p.x & 0x3FFFF, p.y);
    }
}

// ---------------------------------------------------------------------------
// gather core: wave per row; lane = g*16+q. Unroll 32: 4x int4 pair loads
// (16B-aligned: row starts even) + 8 independent 128B gathers in flight.
// ---------------------------------------------------------------------------
__device__ __forceinline__ float4 gather_row(int s, int e, int g, int q,
                                             const int2* __restrict__ pair,
                                             const uint2* __restrict__ hb) {
    float4 av = make_float4(0.f, 0.f, 0.f, 0.f);
    int i = s;
    for (; i + 32 <= e; i += 32) {
        int4 pp0 = *(const int4*)(pair + i      + 2*g);
        int4 pp1 = *(const int4*)(pair + i +  8 + 2*g);
        int4 pp2 = *(const int4*)(pair + i + 16 + 2*g);
        int4 pp3 = *(const int4*)(pair + i + 24 + 2*g);
        uint2 u0 = hb[(size_t)pp0.x * 16 + q];
        uint2 u1 = hb[(size_t)pp0.z * 16 + q];
        uint2 u2 = hb[(size_t)pp1.x * 16 + q];
        uint2 u3 = hb[(size_t)pp1.z * 16 + q];
        uint2 u4 = hb[(size_t)pp2.x * 16 + q];
        uint2 u5 = hb[(size_t)pp2.z * 16 + q];
        uint2 u6 = hb[(size_t)pp3.x * 16 + q];
        uint2 u7 = hb[(size_t)pp3.z * 16 + q];
        fma4v(__int_as_float(pp0.y), bf2f4(u0), av);
        fma4v(__int_as_float(pp0.w), bf2f4(u1), av);
        fma4v(__int_as_float(pp1.y), bf2f4(u2), av);
        fma4v(__int_as_float(pp1.w), bf2f4(u3), av);
        fma4v(__int_as_float(pp2.y), bf2f4(u4), av);
        fma4v(__int_as_float(pp2.w), bf2f4(u5), av);
        fma4v(__int_as_float(pp3.y), bf2f4(u6), av);
        fma4v(__int_as_float(pp3.w), bf2f4(u7), av);
    }
    if (i + 16 <= e) {
        int4 pp0 = *(const int4*)(pair + i     + 2*g);
        int4 pp1 = *(const int4*)(pair + i + 8 + 2*g);
        uint2 u0 = hb[(size_t)pp0.x * 16 + q];
        uint2 u1 = hb[(size_t)pp0.z * 16 + q];
        uint2 u2 = hb[(size_t)pp1.x * 16 + q];
        uint2 u3 = hb[(size_t)pp1.z * 16 + q];
        fma4v(__int_as_float(pp0.y), bf2f4(u0), av);
        fma4v(__int_as_float(pp0.w), bf2f4(u1), av);
        fma4v(__int_as_float(pp1.y), bf2f4(u2), av);
        fma4v(__int_as_float(pp1.w), bf2f4(u3), av);
        i += 16;
    }
    if (i + 8 <= e) {
        int4 pp0 = *(const int4*)(pair + i + 2*g);
        uint2 u0 = hb[(size_t)pp0.x * 16 + q];
        uint2 u1 = hb[(size_t)pp0.z * 16 + q];
        fma4v(__int_as_float(pp0.y), bf2f4(u0), av);
        fma4v(__int_as_float(pp0.w), bf2f4(u1), av);
        i += 8;
    }
    if (i + 4 <= e) {
        int2 p0 = pair[i + g];
        uint2 u0 = hb[(size_t)p0.x * 16 + q];
        fma4v(__int_as_float(p0.y), bf2f4(u0), av);
        i += 4;
    }
    if (i < e) {
        int idx = i + g;
        int2 pD = pair[(idx < e) ? idx : (e - 1)];
        float vD = (idx < e) ? __int_as_float(pD.y) : 0.0f;
        uint2 uD = hb[(size_t)pD.x * 16 + q];
        fma4v(vD, bf2f4(uD), av);
    }
    av.x += __shfl_xor(av.x, 32, 64);
    av.y += __shfl_xor(av.y, 32, 64);
    av.z += __shfl_xor(av.z, 32, 64);
    av.w += __shfl_xor(av.w, 32, 64);
    av.x += __shfl_xor(av.x, 16, 64);
    av.y += __shfl_xor(av.y, 16, 64);
    av.z += __shfl_xor(av.z, 16, 64);
    av.w += __shfl_xor(av.w, 16, 64);
    return av;
}

// ---------------------------------------------------------------------------
// spmm layer: hn = bf16(A * hb)
// ---------------------------------------------------------------------------
__global__ void spmm_kernel(const int* __restrict__ row_start,
                            const int* __restrict__ row_cnt,
                            const int2* __restrict__ pair,
                            const uint2* __restrict__ hb,
                            uint2* __restrict__ hn) {
    int wid  = (int)(((size_t)blockIdx.x * blockDim.x + threadIdx.x) >> 6);
    int lane = threadIdx.x & 63;
    int g = lane >> 4, q = lane & 15;
    if (wid >= N_NODES) return;
    int s = row_start[wid];
    int e = s + row_cnt[wid];

    float4 av = gather_row(s, e, g, q, pair, hb);

    if (lane < 16)
        hn[(size_t)wid * 16 + q] = f42bf(av);
}

// ---------------------------------------------------------------------------
// fused final+dot: one wave per query. fin = 0.25*(ego + hA + hB + A*hB).
// ---------------------------------------------------------------------------
__device__ __forceinline__ float4 fin_row(int row, int g, int q, int lane,
                                          const int* __restrict__ row_start,
                                          const int* __restrict__ row_cnt,
                                          const int2* __restrict__ pair,
                                          const uint2* __restrict__ hA,
                                          const uint2* __restrict__ hB,
                                          const float4* __restrict__ ue4,
                                          const float4* __restrict__ ie4) {
    int s = row_start[row];
    int e = s + row_cnt[row];
    float4 av = gather_row(s, e, g, q, pair, hB);
    float4 f = make_float4(0.f, 0.f, 0.f, 0.f);
    if (lane < 16) {
        size_t o = (size_t)row * 16 + q;
        float4 ego = (row < NUM_USERS)
                   ? ue4[(size_t)row * 16 + q]
                   : ie4[(size_t)(row - NUM_USERS) * 16 + q];
        float4 a1 = bf2f4(hA[o]);
        float4 a2 = bf2f4(hB[o]);
        f.x = 0.25f * (ego.x + a1.x + a2.x + av.x);
        f.y = 0.25f * (ego.y + a1.y + a2.y + av.y);
        f.z = 0.25f * (ego.z + a1.z + a2.z + av.z);
        f.w = 0.25f * (ego.w + a1.w + a2.w + av.w);
    }
    return f;
}

__global__ void score_kernel(const int* __restrict__ row_start,
                             const int* __restrict__ row_cnt,
                             const int2* __restrict__ pair,
                             const uint2* __restrict__ hA,
                             const uint2* __restrict__ hB,
                             const float4* __restrict__ ue4,
                             const float4* __restrict__ ie4,
                             const int* __restrict__ users,
                             const int* __restrict__ items,
                             float* __restrict__ out) {
    int qid  = (int)(((size_t)blockIdx.x * blockDim.x + threadIdx.x) >> 6);
    int lane = threadIdx.x & 63;
    int g = lane >> 4, q = lane & 15;
    if (qid >= N_QUERY) return;

    int urow = users[qid];
    int irow = NUM_USERS + items[qid];

    float4 fu = fin_row(urow, g, q, lane, row_start, row_cnt, pair, hA, hB, ue4, ie4);
    float4 fi = fin_row(irow, g, q, lane, row_start, row_cnt, pair, hA, hB, ue4, ie4);

    float p = fu.x * fi.x + fu.y * fi.y + fu.z * fi.z + fu.w * fi.w;
    p += __shfl_xor(p, 8, 64);
    p += __shfl_xor(p, 4, 64);
    p += __shfl_xor(p, 2, 64);
    p += __shfl_xor(p, 1, 64);

    if (lane == 0)
        out[qid] = p;
}

// ---------------------------------------------------------------------------
extern "C" void kernel_launch(void* const* d_in, const int* in_sizes, int n_in,
                              void* d_out, int out_size, void* d_ws, size_t ws_size,
                              hipStream_t stream) {
    const int*   users = (const int*)  d_in[0];
    const int*   items = (const int*)  d_in[1];
    const float* ue    = (const float*)d_in[2];
    const float* ie    = (const float*)d_in[3];
    const int*   rows  = (const int*)  d_in[4];
    const int*   cols  = (const int*)  d_in[5];
    const float* vals  = (const float*)d_in[6];
    float*       out   = (float*)d_out;

    const size_t REC_N = (size_t)NBUCKET * BUCKET_CAP;   // 5,373,952

    // workspace layout (~156 MB):
    //   ego_bf | hA_bf | hB_bf | rec | pair | recRl | ints
    uint2* ego_bf = (uint2*)d_ws;                        // 19.2 MB
    uint2* hA_bf  = ego_bf + NODE_FLOAT4;                // 19.2 MB
    uint2* hB_bf  = hA_bf + NODE_FLOAT4;                 // 19.2 MB
    int2*  rec    = (int2*)(hB_bf + NODE_FLOAT4);        // 43.0 MB
    int2*  pair   = rec + REC_N;                         // 43.0 MB
    unsigned short* recRl = (unsigned short*)(pair + REC_N);  // 10.7 MB

    int* row_start = (int*)(recRl + REC_N);              // 150,016 i
    int* row_cnt   = row_start + 150016;                 // 150,016 i
    int* gcur      = row_cnt + 150016;                   // 512 i

    (void)hipMemsetAsync(gcur, 0, NBUCKET * sizeof(int), stream);

    bin_kernel<<<BIN_BLOCKS, BIN_THREADS, 0, stream>>>(rows, cols, vals, gcur,
                                                       rec, recRl);
    csr_kernel<<<NBUCKET, CSR_THREADS, 0, stream>>>(rec, recRl, gcur,
        row_start, row_cnt, pair, (const float4*)ue, (const float4*)ie, ego_bf);

    int spmm_blocks = (N_NODES * 64 + 255) / 256;
    spmm_kernel<<<spmm_blocks, 256, 0, stream>>>(row_start, row_cnt, pair, ego_bf, hA_bf);
    spmm_kernel<<<spmm_blocks, 256, 0, stream>>>(row_start, row_cnt, pair, hA_bf, hB_bf);

    int score_blocks = (N_QUERY * 64 + 255) / 256;       // 4096
    score_kernel<<<score_blocks, 256, 0, stream>>>(row_start, row_cnt, pair,
        hA_bf, hB_bf, (const float4*)ue, (const float4*)ie, users, items, out);
}

// Round 15
// 315.289 us; speedup vs baseline: 1.0480x; 1.0480x over previous
//
#include <hip/hip_runtime.h>

#define NUM_USERS 100000
#define NUM_ITEMS 50000
#define EMBED_DIM 64
#define N_NODES   (NUM_USERS + NUM_ITEMS)      // 150000
#define N_EDGES   4800000
#define N_QUERY   16384

#define NODE_FLOATS ((size_t)N_NODES * EMBED_DIM)   // 9,600,000
#define NODE_FLOAT4 (NODE_FLOATS / 4)                // 2,400,000

#define NBUCKET    256
#define BROWS      586                               // 256*586 = 150016 rows
#define BUCKET_CAP 20480
#define BIN_EDGES  4096
#define BIN_THREADS 512
#define BIN_BLOCKS ((N_EDGES + BIN_EDGES - 1) / BIN_EDGES)  // 1172
#define CSR_THREADS 512
#define EGO_SLICE  (NODE_FLOAT4 / NBUCKET)            // 9375 float4 per csr block

// ---------------------------------------------------------------------------
// bf16 pack/unpack helpers (RNE)
// ---------------------------------------------------------------------------
__device__ __forceinline__ float4 bf2f4(uint2 u) {
    float4 f;
    f.x = __uint_as_float(u.x << 16);
    f.y = __uint_as_float(u.x & 0xFFFF0000u);
    f.z = __uint_as_float(u.y << 16);
    f.w = __uint_as_float(u.y & 0xFFFF0000u);
    return f;
}
__device__ __forceinline__ unsigned rne_bf(float f) {
    unsigned b = __float_as_uint(f);
    return (b + 0x7FFFu + ((b >> 16) & 1u)) >> 16;
}
__device__ __forceinline__ uint2 f42bf(float4 f) {
    uint2 u;
    u.x = rne_bf(f.x) | (rne_bf(f.y) << 16);
    u.y = rne_bf(f.z) | (rne_bf(f.w) << 16);
    return u;
}
__device__ __forceinline__ void fma4v(float v, float4 xv, float4& av) {
    av.x = fmaf(v, xv.x, av.x);
    av.y = fmaf(v, xv.y, av.y);
    av.z = fmaf(v, xv.z, av.z);
    av.w = fmaf(v, xv.w, av.w);
}

// ---------------------------------------------------------------------------
// bin: single edge read -> 256 row-range buckets (LDS-staged). Dense
// copy-out; also emits u16 row-local ids (recRl) for csr's cheap hist.
// 4096 edges/block @ 41 KB LDS -> 3 blocks/CU.
// ---------------------------------------------------------------------------
__global__ void __launch_bounds__(BIN_THREADS) bin_kernel(
        const int* __restrict__ rows,
        const int* __restrict__ cols,
        const float* __restrict__ vals,
        int* __restrict__ gcur,
        int2* __restrict__ rec,
        unsigned short* __restrict__ recRl) {
    __shared__ int  lcnt[NBUCKET];
    __shared__ int  lbase[NBUCKET];
    __shared__ int  loff[NBUCKET];
    __shared__ int  lcur[NBUCKET];
    __shared__ int  scan[NBUCKET];
    __shared__ int2 sRec[BIN_EDGES];
    __shared__ unsigned char sBkt[BIN_EDGES];

    const int tid = threadIdx.x;
    if (tid < NBUCKET) lcnt[tid] = 0;
    __syncthreads();

    const size_t e0 = (size_t)blockIdx.x * BIN_EDGES;
    const int nrec = (int)(((size_t)N_EDGES - e0) < BIN_EDGES ? (N_EDGES - e0)
                                                              : BIN_EDGES);

    // pass 1: bucket counts
    for (int k = tid; k < nrec; k += BIN_THREADS)
        atomicAdd(&lcnt[rows[e0 + k] / BROWS], 1);
    __syncthreads();

    // claim global ranges (gcur zero-based; add bucket region base)
    if (tid < NBUCKET) {
        lbase[tid] = tid * BUCKET_CAP + atomicAdd(&gcur[tid], lcnt[tid]);
        scan[tid]  = lcnt[tid];
    }
    __syncthreads();
    for (int off = 1; off < NBUCKET; off <<= 1) {
        int tv = (tid < NBUCKET && tid >= off) ? scan[tid - off] : 0;
        __syncthreads();
        if (tid < NBUCKET) scan[tid] += tv;
        __syncthreads();
    }
    if (tid < NBUCKET) {
        loff[tid] = scan[tid] - lcnt[tid];
        lcur[tid] = loff[tid];
    }
    __syncthreads();

    // pass 2: stage records bucket-sorted in LDS, record bucket per slot
    for (int k = tid; k < nrec; k += BIN_THREADS) {
        int r  = rows[e0 + k];
        int b  = r / BROWS;
        int rl = r - b * BROWS;
        int slot = atomicAdd(&lcur[b], 1);
        sRec[slot] = make_int2((rl << 18) | cols[e0 + k],
                               __float_as_int(vals[e0 + k]));
        sBkt[slot] = (unsigned char)b;
    }
    __syncthreads();

    // dense coalesced copy-out (+ u16 row-local id stream)
    for (int k = tid; k < nrec; k += BIN_THREADS) {
        int bk = sBkt[k];
        int2 r = sRec[k];
        size_t d = (size_t)lbase[bk] + (k - loff[bk]);
        rec[d]   = r;
        recRl[d] = (unsigned short)((unsigned)r.x >> 18);
    }
}

// ---------------------------------------------------------------------------
// csr: one block per bucket, 512 threads (8 waves/CU). Hist reads the u16
// recRl stream; scan (even-aligned starts); LDS-cursor scatter into the
// bucket's pair slice. Fused ego bf16 conversion.
// ---------------------------------------------------------------------------
__global__ void __launch_bounds__(CSR_THREADS) csr_kernel(
        const int2* __restrict__ rec,
        const unsigned short* __restrict__ recRl,
        const int* __restrict__ gcur,
        int* __restrict__ row_start,
        int* __restrict__ row_cnt,
        int2* __restrict__ pair,
        const float4* __restrict__ ue4,
        const float4* __restrict__ ie4,
        uint2* __restrict__ ego) {
    __shared__ int hist[BROWS + 2];
    __shared__ int excl[1024];
    __shared__ int part[CSR_THREADS];

    const int b    = blockIdx.x;
    const int base = b * BUCKET_CAP;
    const int n    = gcur[b];
    const int lo   = b * BROWS;
    const int t    = threadIdx.x;

    // fused ego bf16 conversion (independent; overlaps hist latency)
    {
        const size_t user_f4 = (size_t)NUM_USERS * EMBED_DIM / 4;
        size_t s0 = (size_t)b * EGO_SLICE;
        for (int j = t; j < EGO_SLICE; j += CSR_THREADS) {
            size_t idx = s0 + j;
            float4 v = (idx < user_f4) ? ue4[idx] : ie4[idx - user_f4];
            ego[idx] = f42bf(v);
        }
    }

    for (int j = t; j < BROWS; j += CSR_THREADS) hist[j] = 0;
    __syncthreads();

    // pass 1: histogram from the compact u16 stream
    for (int i = t; i < n; i += CSR_THREADS)
        atomicAdd(&hist[recRl[base + i]], 1);
    __syncthreads();

    // exclusive scan of even-rounded counts -> even row starts (2/thread)
    int vloc[2];
    int s0 = 0;
    #pragma unroll
    for (int k = 0; k < 2; ++k) {
        int idx = t * 2 + k;
        int v = (idx < BROWS) ? ((hist[idx] + 1) & ~1) : 0;
        vloc[k] = s0;
        s0 += v;
    }
    part[t] = s0;
    __syncthreads();
    for (int off = 1; off < CSR_THREADS; off <<= 1) {
        int tv = (t >= off) ? part[t - off] : 0;
        __syncthreads();
        part[t] += tv;
        __syncthreads();
    }
    int pbase = part[t] - s0;
    #pragma unroll
    for (int k = 0; k < 2; ++k) {
        int idx = t * 2 + k;
        if (idx < BROWS) excl[idx] = pbase + vloc[k];
    }
    __syncthreads();

    for (int j = t; j < BROWS; j += CSR_THREADS) {
        row_start[lo + j] = base + excl[j];
        row_cnt[lo + j]   = hist[j];
    }
    __syncthreads();

    // pass 2: scatter; excl doubles as cursors
    for (int i = t; i < n; i += CSR_THREADS) {
        int2 p = rec[base + i];
        int rl = (unsigned)p.x >> 18;
        int slot = atomicAdd(&excl[rl], 1);
        pair[(size_t)base + slot] = make_int2(p.x & 0x3FFFF, p.y);
    }
}

// ---------------------------------------------------------------------------
// gather core: wave per row; lane = g*16+q. Unroll 32: 4x int4 pair loads
// (16B-aligned: row starts even) + 8 independent 128B gathers in flight.
// Returns reduced row float4 (valid lanes 0..15).
// ---------------------------------------------------------------------------
__device__ __forceinline__ float4 gather_row(int s, int e, int g, int q,
                                             const int2* __restrict__ pair,
                                             const uint2* __restrict__ hb) {
    float4 av = make_float4(0.f, 0.f, 0.f, 0.f);
    int i = s;
    for (; i + 32 <= e; i += 32) {
        int4 pp0 = *(const int4*)(pair + i      + 2*g);
        int4 pp1 = *(const int4*)(pair + i +  8 + 2*g);
        int4 pp2 = *(const int4*)(pair + i + 16 + 2*g);
        int4 pp3 = *(const int4*)(pair + i + 24 + 2*g);
        uint2 u0 = hb[(size_t)pp0.x * 16 + q];
        uint2 u1 = hb[(size_t)pp0.z * 16 + q];
        uint2 u2 = hb[(size_t)pp1.x * 16 + q];
        uint2 u3 = hb[(size_t)pp1.z * 16 + q];
        uint2 u4 = hb[(size_t)pp2.x * 16 + q];
        uint2 u5 = hb[(size_t)pp2.z * 16 + q];
        uint2 u6 = hb[(size_t)pp3.x * 16 + q];
        uint2 u7 = hb[(size_t)pp3.z * 16 + q];
        fma4v(__int_as_float(pp0.y), bf2f4(u0), av);
        fma4v(__int_as_float(pp0.w), bf2f4(u1), av);
        fma4v(__int_as_float(pp1.y), bf2f4(u2), av);
        fma4v(__int_as_float(pp1.w), bf2f4(u3), av);
        fma4v(__int_as_float(pp2.y), bf2f4(u4), av);
        fma4v(__int_as_float(pp2.w), bf2f4(u5), av);
        fma4v(__int_as_float(pp3.y), bf2f4(u6), av);
        fma4v(__int_as_float(pp3.w), bf2f4(u7), av);
    }
    if (i + 16 <= e) {
        int4 pp0 = *(const int4*)(pair + i     + 2*g);
        int4 pp1 = *(const int4*)(pair + i + 8 + 2*g);
        uint2 u0 = hb[(size_t)pp0.x * 16 + q];
        uint2 u1 = hb[(size_t)pp0.z * 16 + q];
        uint2 u2 = hb[(size_t)pp1.x * 16 + q];
        uint2 u3 = hb[(size_t)pp1.z * 16 + q];
        fma4v(__int_as_float(pp0.y), bf2f4(u0), av);
        fma4v(__int_as_float(pp0.w), bf2f4(u1), av);
        fma4v(__int_as_float(pp1.y), bf2f4(u2), av);
        fma4v(__int_as_float(pp1.w), bf2f4(u3), av);
        i += 16;
    }
    if (i + 8 <= e) {
        int4 pp0 = *(const int4*)(pair + i + 2*g);
        uint2 u0 = hb[(size_t)pp0.x * 16 + q];
        uint2 u1 = hb[(size_t)pp0.z * 16 + q];
        fma4v(__int_as_float(pp0.y), bf2f4(u0), av);
        fma4v(__int_as_float(pp0.w), bf2f4(u1), av);
        i += 8;
    }
    if (i + 4 <= e) {
        int2 p0 = pair[i + g];
        uint2 u0 = hb[(size_t)p0.x * 16 + q];
        fma4v(__int_as_float(p0.y), bf2f4(u0), av);
        i += 4;
    }
    if (i < e) {
        int idx = i + g;
        int2 pD = pair[(idx < e) ? idx : (e - 1)];
        float vD = (idx < e) ? __int_as_float(pD.y) : 0.0f;
        uint2 uD = hb[(size_t)pD.x * 16 + q];
        fma4v(vD, bf2f4(uD), av);
    }
    av.x += __shfl_xor(av.x, 32, 64);
    av.y += __shfl_xor(av.y, 32, 64);
    av.z += __shfl_xor(av.z, 32, 64);
    av.w += __shfl_xor(av.w, 32, 64);
    av.x += __shfl_xor(av.x, 16, 64);
    av.y += __shfl_xor(av.y, 16, 64);
    av.z += __shfl_xor(av.z, 16, 64);
    av.w += __shfl_xor(av.w, 16, 64);
    return av;
}

// ---------------------------------------------------------------------------
// spmm layer: hn = bf16(A * hb)
// ---------------------------------------------------------------------------
__global__ void spmm_kernel(const int* __restrict__ row_start,
                            const int* __restrict__ row_cnt,
                            const int2* __restrict__ pair,
                            const uint2* __restrict__ hb,
                            uint2* __restrict__ hn) {
    int wid  = (int)(((size_t)blockIdx.x * blockDim.x + threadIdx.x) >> 6);
    int lane = threadIdx.x & 63;
    int g = lane >> 4, q = lane & 15;
    if (wid >= N_NODES) return;
    int s = row_start[wid];
    int e = s + row_cnt[wid];

    float4 av = gather_row(s, e, g, q, pair, hb);

    if (lane < 16)
        hn[(size_t)wid * 16 + q] = f42bf(av);
}

// ---------------------------------------------------------------------------
// fused final+dot: one wave per query. fin = 0.25*(ego + hA + hB + A*hB).
// ---------------------------------------------------------------------------
__device__ __forceinline__ float4 fin_row(int row, int g, int q, int lane,
                                          const int* __restrict__ row_start,
                                          const int* __restrict__ row_cnt,
                                          const int2* __restrict__ pair,
                                          const uint2* __restrict__ hA,
                                          const uint2* __restrict__ hB,
                                          const float4* __restrict__ ue4,
                                          const float4* __restrict__ ie4) {
    int s = row_start[row];
    int e = s + row_cnt[row];
    float4 av = gather_row(s, e, g, q, pair, hB);
    float4 f = make_float4(0.f, 0.f, 0.f, 0.f);
    if (lane < 16) {
        size_t o = (size_t)row * 16 + q;
        float4 ego = (row < NUM_USERS)
                   ? ue4[(size_t)row * 16 + q]
                   : ie4[(size_t)(row - NUM_USERS) * 16 + q];
        float4 a1 = bf2f4(hA[o]);
        float4 a2 = bf2f4(hB[o]);
        f.x = 0.25f * (ego.x + a1.x + a2.x + av.x);
        f.y = 0.25f * (ego.y + a1.y + a2.y + av.y);
        f.z = 0.25f * (ego.z + a1.z + a2.z + av.z);
        f.w = 0.25f * (ego.w + a1.w + a2.w + av.w);
    }
    return f;
}

__global__ void score_kernel(const int* __restrict__ row_start,
                             const int* __restrict__ row_cnt,
                             const int2* __restrict__ pair,
                             const uint2* __restrict__ hA,
                             const uint2* __restrict__ hB,
                             const float4* __restrict__ ue4,
                             const float4* __restrict__ ie4,
                             const int* __restrict__ users,
                             const int* __restrict__ items,
                             float* __restrict__ out) {
    int qid  = (int)(((size_t)blockIdx.x * blockDim.x + threadIdx.x) >> 6);
    int lane = threadIdx.x & 63;
    int g = lane >> 4, q = lane & 15;
    if (qid >= N_QUERY) return;

    int urow = users[qid];
    int irow = NUM_USERS + items[qid];

    float4 fu = fin_row(urow, g, q, lane, row_start, row_cnt, pair, hA, hB, ue4, ie4);
    float4 fi = fin_row(irow, g, q, lane, row_start, row_cnt, pair, hA, hB, ue4, ie4);

    float p = fu.x * fi.x + fu.y * fi.y + fu.z * fi.z + fu.w * fi.w;
    p += __shfl_xor(p, 8, 64);
    p += __shfl_xor(p, 4, 64);
    p += __shfl_xor(p, 2, 64);
    p += __shfl_xor(p, 1, 64);

    if (lane == 0)
        out[qid] = p;
}

// ---------------------------------------------------------------------------
extern "C" void kernel_launch(void* const* d_in, const int* in_sizes, int n_in,
                              void* d_out, int out_size, void* d_ws, size_t ws_size,
                              hipStream_t stream) {
    const int*   users = (const int*)  d_in[0];
    const int*   items = (const int*)  d_in[1];
    const float* ue    = (const float*)d_in[2];
    const float* ie    = (const float*)d_in[3];
    const int*   rows  = (const int*)  d_in[4];
    const int*   cols  = (const int*)  d_in[5];
    const float* vals  = (const float*)d_in[6];
    float*       out   = (float*)d_out;

    const size_t REC_N = (size_t)NBUCKET * BUCKET_CAP;   // 5,242,880

    // workspace layout (~155 MB):
    //   ego_bf | hA_bf | hB_bf | rec | pair | recRl | ints
    uint2* ego_bf = (uint2*)d_ws;                        // 19.2 MB
    uint2* hA_bf  = ego_bf + NODE_FLOAT4;                // 19.2 MB
    uint2* hB_bf  = hA_bf + NODE_FLOAT4;                 // 19.2 MB
    int2*  rec    = (int2*)(hB_bf + NODE_FLOAT4);        // 41.9 MB
    int2*  pair   = rec + REC_N;                         // 41.9 MB
    unsigned short* recRl = (unsigned short*)(pair + REC_N);  // 10.5 MB

    int* row_start = (int*)(recRl + REC_N);              // 150,016 i
    int* row_cnt   = row_start + 150016;                 // 150,016 i
    int* gcur      = row_cnt + 150016;                   // 256 i

    (void)hipMemsetAsync(gcur, 0, NBUCKET * sizeof(int), stream);

    bin_kernel<<<BIN_BLOCKS, BIN_THREADS, 0, stream>>>(rows, cols, vals, gcur,
                                                       rec, recRl);
    csr_kernel<<<NBUCKET, CSR_THREADS, 0, stream>>>(rec, recRl, gcur,
        row_start, row_cnt, pair, (const float4*)ue, (const float4*)ie, ego_bf);

    int spmm_blocks = (N_NODES * 64 + 255) / 256;
    spmm_kernel<<<spmm_blocks, 256, 0, stream>>>(row_start, row_cnt, pair, ego_bf, hA_bf);
    spmm_kernel<<<spmm_blocks, 256, 0, stream>>>(row_start, row_cnt, pair, hA_bf, hB_bf);

    int score_blocks = (N_QUERY * 64 + 255) / 256;       // 4096
    score_kernel<<<score_blocks, 256, 0, stream>>>(row_start, row_cnt, pair,
        hA_bf, hB_bf, (const float4*)ue, (const float4*)ie, users, items, out);
}